// Round 1
// baseline (1197.455 us; speedup 1.0000x reference)
//
#include <hip/hip_runtime.h>
#include <hip/hip_bf16.h>

#define S_LEN 2048
#define HIDDEN 2048
#define NHEAD 16
#define NKVH 4
#define HEADD 128
#define BATCH 2

typedef __attribute__((ext_vector_type(4))) float f32x4;
typedef __attribute__((ext_vector_type(8))) short bf16x8;
typedef __attribute__((ext_vector_type(4))) unsigned short u16x4;

__device__ __forceinline__ unsigned short f2bf(float f) {
  union { __hip_bfloat16 h; unsigned short u; } cv;
  cv.h = __float2bfloat16(f);
  return cv.u;
}

__device__ __forceinline__ void gl_lds16(const void* g, void* l) {
  __builtin_amdgcn_global_load_lds(
      (const __attribute__((address_space(1))) unsigned int*)g,
      (__attribute__((address_space(3))) unsigned int*)l,
      16, 0, 0);
}

// ---------------- rope table: [S][64] {cos,sin} ----------------
__global__ void k_rope_table(float* tab) {
  int idx = blockIdx.x * blockDim.x + threadIdx.x;
  if (idx >= S_LEN * 64) return;
  int s = idx >> 6, j = idx & 63;
  float invf = expf(-(float)j * (logf(10000.0f) / 64.0f));
  float ang = (float)s * invf;
  float sn, cs;
  sincosf(ang, &sn, &cs);
  tab[idx * 2 + 0] = cs;
  tab[idx * 2 + 1] = sn;
}

// ---------------- pack X = [xr|xi] -> bf16 [4096][4096] ----------------
__global__ void k_pack_x(const float* __restrict__ xr, const float* __restrict__ xi,
                         unsigned short* __restrict__ Xp) {
  int idx = blockIdx.x * blockDim.x + threadIdx.x;  // over float4 chunks
  if (idx >= 4096 * 4096 / 4) return;
  int m = idx >> 10;          // 1024 chunks per row
  int c4 = idx & 1023;
  const float* src = (c4 < 512) ? (xr + (size_t)m * 2048 + c4 * 4)
                                : (xi + (size_t)m * 2048 + (c4 - 512) * 4);
  f32x4 v = *(const f32x4*)src;
  ((u16x4*)Xp)[idx] = (u16x4){f2bf(v.x), f2bf(v.y), f2bf(v.z), f2bf(v.w)};
}

// ---------------- pack weights transposed bf16: Wt[n][k], n in [0,10240) ----------------
// rows 0..6143: QKV combined B^T; rows 6144..10239: O B^T
__global__ void k_pack_w(const float* __restrict__ wq_r, const float* __restrict__ wq_i,
                         const float* __restrict__ wk_r, const float* __restrict__ wk_i,
                         const float* __restrict__ wv_r, const float* __restrict__ wv_i,
                         const float* __restrict__ wo_r, const float* __restrict__ wo_i,
                         unsigned short* __restrict__ Wt) {
  __shared__ float tile[32][33];
  int k0 = blockIdx.x * 32;
  int n0 = blockIdx.y * 32;
  int tx = threadIdx.x, ty0 = threadIdx.y;
#pragma unroll
  for (int i = 0; i < 4; ++i) {
    int ty = ty0 + i * 8;
    int k = k0 + ty;
    int n = n0 + tx;
    const float* Wr; const float* Wi; int w, t, part, j;
    if (n < 4096)      { Wr = wq_r; Wi = wq_i; w = 2048; t = n;        }
    else if (n < 5120) { Wr = wk_r; Wi = wk_i; w = 512;  t = n - 4096; }
    else if (n < 6144) { Wr = wv_r; Wi = wv_i; w = 512;  t = n - 5120; }
    else               { Wr = wo_r; Wi = wo_i; w = 2048; t = n - 6144; }
    part = (t >= w); j = part ? (t - w) : t;
    float v;
    if (part == 0) v = (k < 2048) ? Wr[(size_t)k * w + j] : -Wi[(size_t)(k - 2048) * w + j];
    else           v = (k < 2048) ? Wi[(size_t)k * w + j] :  Wr[(size_t)(k - 2048) * w + j];
    tile[ty][tx] = v;
  }
  __syncthreads();
#pragma unroll
  for (int i = 0; i < 4; ++i) {
    int ty = ty0 + i * 8;
    Wt[(size_t)(n0 + ty) * 4096 + k0 + tx] = f2bf(tile[tx][ty]);
  }
}

// ---------------- generic bf16 MFMA GEMM: C[M,N] = A[M,K] @ Bt[N,K]^T ----------------
// mode 0: plain f32 store to Cout (ldc)
// mode 1: O-proj epilogue: split r/i + bias -> outR/outI [4096][2048]
// mode 2: scores: per-z (b,h); scale + causal mask; store f32 into attn
__global__ __launch_bounds__(256) void k_gemm(
    const unsigned short* __restrict__ Aall, int lda,
    const unsigned short* __restrict__ Ball, int ldb,
    float* __restrict__ Cout, int ldc, int K, int mode,
    float* __restrict__ outR, float* __restrict__ outI,
    const float* __restrict__ bR, const float* __restrict__ bI) {
  __shared__ __align__(16) unsigned short sA[128 * 32];
  __shared__ __align__(16) unsigned short sB[128 * 32];
  int tid = threadIdx.x, lane = tid & 63, wid = tid >> 6;
  int n0 = blockIdx.x * 128, m0 = blockIdx.y * 128;
  const unsigned short* A = Aall;
  const unsigned short* Bt = Ball;
  float* Cp = Cout;
  if (mode == 2) {
    int bh = blockIdx.z;
    int b = bh >> 4, h = bh & 15;
    A = Aall + (size_t)bh * S_LEN * 256;
    Bt = Ball + (size_t)(b * NKVH + (h >> 2)) * S_LEN * 256;
    Cp = Cout + (size_t)bh * S_LEN * S_LEN;
    if (n0 >= m0 + 128) {  // fully masked tile: write zero probs
      const f32x4 z = {0.f, 0.f, 0.f, 0.f};
#pragma unroll
      for (int i = 0; i < 16; ++i) {
        int c = tid + 256 * i;
        int r = c >> 5, cc = c & 31;
        *(f32x4*)(Cp + (size_t)(m0 + r) * S_LEN + n0 + cc * 4) = z;
      }
      return;
    }
  }
  int wr = wid >> 1, wc = wid & 1;
  const f32x4 fz = {0.f, 0.f, 0.f, 0.f};
  f32x4 acc[4][4];
#pragma unroll
  for (int i = 0; i < 4; ++i)
#pragma unroll
    for (int j = 0; j < 4; ++j) acc[i][j] = fz;

  const char* Abase = (const char*)A + (size_t)m0 * lda * 2;
  const char* Bbase = (const char*)Bt + (size_t)n0 * ldb * 2;
  for (int k0 = 0; k0 < K; k0 += 32) {
    __syncthreads();
    {
      int c0 = tid, c1 = tid + 256;
      const char* Ab = Abase + (size_t)k0 * 2;
      const char* Bb = Bbase + (size_t)k0 * 2;
      gl_lds16(Ab + (size_t)(c0 >> 2) * lda * 2 + (c0 & 3) * 16, (char*)sA + wid * 1024);
      gl_lds16(Ab + (size_t)(c1 >> 2) * lda * 2 + (c1 & 3) * 16, (char*)sA + 4096 + wid * 1024);
      gl_lds16(Bb + (size_t)(c0 >> 2) * ldb * 2 + (c0 & 3) * 16, (char*)sB + wid * 1024);
      gl_lds16(Bb + (size_t)(c1 >> 2) * ldb * 2 + (c1 & 3) * 16, (char*)sB + 4096 + wid * 1024);
    }
    __syncthreads();
    const char* aw = (const char*)sA + wr * 64 * 64;
    const char* bw = (const char*)sB + wc * 64 * 64;
    int lrow = lane & 15, lkb = (lane >> 4) * 16;
    bf16x8 af[4], bfr[4];
#pragma unroll
    for (int i = 0; i < 4; ++i) af[i] = *(const bf16x8*)(aw + (i * 16 + lrow) * 64 + lkb);
#pragma unroll
    for (int i = 0; i < 4; ++i) bfr[i] = *(const bf16x8*)(bw + (i * 16 + lrow) * 64 + lkb);
#pragma unroll
    for (int i = 0; i < 4; ++i)
#pragma unroll
      for (int j = 0; j < 4; ++j)
        acc[i][j] = __builtin_amdgcn_mfma_f32_16x16x32_bf16(af[i], bfr[j], acc[i][j], 0, 0, 0);
  }
  int r0 = (lane >> 4) * 4, col = lane & 15;
  const float scale = 0.08838834764831845f;  // 1/sqrt(128)
#pragma unroll
  for (int i = 0; i < 4; ++i)
#pragma unroll
    for (int j = 0; j < 4; ++j) {
      int gmb = m0 + wr * 64 + i * 16 + r0;
      int gn = n0 + wc * 64 + j * 16 + col;
#pragma unroll
      for (int r = 0; r < 4; ++r) {
        float v = acc[i][j][r];
        int gm = gmb + r;
        if (mode == 0) {
          Cp[(size_t)gm * ldc + gn] = v;
        } else if (mode == 1) {
          if (gn < 2048) outR[(size_t)gm * 2048 + gn] = v + bR[gn];
          else           outI[(size_t)gm * 2048 + (gn - 2048)] = v + bI[gn - 2048];
        } else {
          v *= scale;
          if (gn > gm) v = 0.0f;
          Cp[(size_t)gm * S_LEN + gn] = v;
        }
      }
    }
}

// ---------------- rope + pack Q: Qcat[b,h][s][256] bf16 ----------------
__global__ void k_rope_q(const float* __restrict__ QKVf, const float* __restrict__ tab,
                         const float* __restrict__ bqr, const float* __restrict__ bqi,
                         unsigned short* __restrict__ Qcat) {
  int idx = blockIdx.x * blockDim.x + threadIdx.x;  // B*S*NH*HD = 8388608
  if (idx >= BATCH * S_LEN * NHEAD * HEADD) return;
  int d = idx & 127;
  int h = (idx >> 7) & 15;
  int s = (idx >> 11) & 2047;
  int b = (idx >> 22) & 1;
  size_t m = (size_t)b * S_LEN + s;
  int colc = h * 128 + d;
  float qr = QKVf[m * 6144 + colc] + bqr[colc];
  float qi = QKVf[m * 6144 + 2048 + colc] + bqi[colc];
  int ti = (s * 64 + (d & 63)) * 2;
  float cs = tab[ti], sn = tab[ti + 1];
  float orr = qr * cs - qi * sn;
  float oii = qr * sn + qi * cs;
  size_t base = ((size_t)(b * NHEAD + h) * S_LEN + s) * 256;
  Qcat[base + d] = f2bf(orr);
  Qcat[base + 128 + d] = f2bf(oii);
}

// ---------------- rope + pack K: Kcat[b,kv][s][256] bf16 ----------------
__global__ void k_rope_k(const float* __restrict__ QKVf, const float* __restrict__ tab,
                         const float* __restrict__ bkr, const float* __restrict__ bki,
                         unsigned short* __restrict__ Kcat) {
  int idx = blockIdx.x * blockDim.x + threadIdx.x;  // B*S*NKV*HD = 2097152
  if (idx >= BATCH * S_LEN * NKVH * HEADD) return;
  int d = idx & 127;
  int kv = (idx >> 7) & 3;
  int s = (idx >> 9) & 2047;
  int b = (idx >> 20) & 1;
  size_t m = (size_t)b * S_LEN + s;
  int jb = kv * 128 + d;
  float kr = QKVf[m * 6144 + 4096 + jb] + bkr[jb];
  float ki = QKVf[m * 6144 + 4608 + jb] + bki[jb];
  int ti = (s * 64 + (d & 63)) * 2;
  float cs = tab[ti], sn = tab[ti + 1];
  float orr = kr * cs - ki * sn;
  float oii = kr * sn + ki * cs;
  size_t base = ((size_t)(b * NKVH + kv) * S_LEN + s) * 256;
  Kcat[base + d] = f2bf(orr);
  Kcat[base + 128 + d] = f2bf(oii);
}

// ---------------- V pack transposed: Vt[b,kv][256][2048] bf16 ----------------
__global__ void k_vpack(const float* __restrict__ QKVf, const float* __restrict__ bvr,
                        const float* __restrict__ bvi, unsigned short* __restrict__ Vt) {
  __shared__ float tile[32][33];
  int s0 = blockIdx.x * 32, n0 = blockIdx.y * 32, bkv = blockIdx.z;
  int b = bkv >> 2, kv = bkv & 3;
  int tx = threadIdx.x, ty0 = threadIdx.y;
#pragma unroll
  for (int i = 0; i < 4; ++i) {
    int ty = ty0 + i * 8;
    int s = s0 + ty, n = n0 + tx;
    int d = n & 127, isI = n >> 7;
    int col = (isI ? 5632 : 5120) + kv * 128 + d;
    float bias = isI ? bvi[kv * 128 + d] : bvr[kv * 128 + d];
    tile[ty][tx] = QKVf[(size_t)(b * S_LEN + s) * 6144 + col] + bias;
  }
  __syncthreads();
#pragma unroll
  for (int i = 0; i < 4; ++i) {
    int ty = ty0 + i * 8;
    Vt[(size_t)(bkv * 256 + n0 + ty) * S_LEN + s0 + tx] = f2bf(tile[tx][ty]);
  }
}

// ---------------- row softmax, in-place over causal prefix ----------------
__global__ __launch_bounds__(256) void k_softmax(float* __restrict__ attn) {
  __shared__ float row[2048];
  __shared__ float red[4];
  int q = blockIdx.x, bh = blockIdx.y;
  float* p = attn + ((size_t)bh * S_LEN + q) * S_LEN;
  int L = q + 1;
  int tid = threadIdx.x, lane = tid & 63, w = tid >> 6;
  float mx = -3.4e38f;
  for (int i = tid; i < L; i += 256) {
    float v = p[i];
    row[i] = v;
    mx = fmaxf(mx, v);
  }
#pragma unroll
  for (int o = 32; o; o >>= 1) mx = fmaxf(mx, __shfl_xor(mx, o));
  if (lane == 0) red[w] = mx;
  __syncthreads();
  mx = fmaxf(fmaxf(red[0], red[1]), fmaxf(red[2], red[3]));
  float sum = 0.f;
  for (int i = tid; i < L; i += 256) {
    float e = __expf(row[i] - mx);
    row[i] = e;
    sum += e;
  }
#pragma unroll
  for (int o = 32; o; o >>= 1) sum += __shfl_xor(sum, o);
  __syncthreads();
  if (lane == 0) red[w] = sum;
  __syncthreads();
  float inv = 1.0f / (red[0] + red[1] + red[2] + red[3]);
  for (int i = tid; i < L; i += 256) p[i] = row[i] * inv;
}

// ---------------- PV: Cpack[b*S+q][4096] bf16 = probs @ [Vr|Vi] ----------------
__global__ __launch_bounds__(256) void k_pv(const float* __restrict__ attn,
                                            const unsigned short* __restrict__ Vt,
                                            unsigned short* __restrict__ Cpack) {
  __shared__ __align__(16) unsigned short sA[128 * 32];
  __shared__ __align__(16) unsigned short sB[128 * 32];
  int tid = threadIdx.x, lane = tid & 63, wid = tid >> 6;
  int nt = blockIdx.x;     // 0..1 (r / i)
  int qt = blockIdx.y;     // 0..15
  int bh = blockIdx.z;     // 0..31
  int b = bh >> 4, h = bh & 15;
  int m0 = qt * 128, n0 = nt * 128;
  const float* P = attn + (size_t)bh * S_LEN * S_LEN;
  const unsigned short* B = Vt + (size_t)(b * NKVH + (h >> 2)) * 256 * S_LEN;
  int wr = wid >> 1, wc = wid & 1;
  const f32x4 fz = {0.f, 0.f, 0.f, 0.f};
  f32x4 acc[4][4];
#pragma unroll
  for (int i = 0; i < 4; ++i)
#pragma unroll
    for (int j = 0; j < 4; ++j) acc[i][j] = fz;
  int kmax = m0 + 128;
  const char* Bbase = (const char*)B + (size_t)n0 * S_LEN * 2;
  for (int k0 = 0; k0 < kmax; k0 += 32) {
    __syncthreads();
#pragma unroll
    for (int i = 0; i < 4; ++i) {
      int c = tid + 256 * i;  // 1024 chunks of 4 floats
      int r = c >> 3, cc = c & 7;
      f32x4 v = *(const f32x4*)(P + (size_t)(m0 + r) * S_LEN + k0 + cc * 4);
      *(u16x4*)((char*)sA + r * 64 + cc * 8) =
          (u16x4){f2bf(v.x), f2bf(v.y), f2bf(v.z), f2bf(v.w)};
    }
    {
      int c0 = tid, c1 = tid + 256;
      const char* Bb = Bbase + (size_t)k0 * 2;
      gl_lds16(Bb + (size_t)(c0 >> 2) * S_LEN * 2 + (c0 & 3) * 16, (char*)sB + wid * 1024);
      gl_lds16(Bb + (size_t)(c1 >> 2) * S_LEN * 2 + (c1 & 3) * 16, (char*)sB + 4096 + wid * 1024);
    }
    __syncthreads();
    const char* aw = (const char*)sA + wr * 64 * 64;
    const char* bw = (const char*)sB + wc * 64 * 64;
    int lrow = lane & 15, lkb = (lane >> 4) * 16;
    bf16x8 af[4], bfr[4];
#pragma unroll
    for (int i = 0; i < 4; ++i) af[i] = *(const bf16x8*)(aw + (i * 16 + lrow) * 64 + lkb);
#pragma unroll
    for (int i = 0; i < 4; ++i) bfr[i] = *(const bf16x8*)(bw + (i * 16 + lrow) * 64 + lkb);
#pragma unroll
    for (int i = 0; i < 4; ++i)
#pragma unroll
      for (int j = 0; j < 4; ++j)
        acc[i][j] = __builtin_amdgcn_mfma_f32_16x16x32_bf16(af[i], bfr[j], acc[i][j], 0, 0, 0);
  }
  int r0 = (lane >> 4) * 4, col = lane & 15;
#pragma unroll
  for (int i = 0; i < 4; ++i)
#pragma unroll
    for (int j = 0; j < 4; ++j) {
      int gmb = m0 + wr * 64 + i * 16 + r0;
      int nn = n0 + wc * 64 + j * 16 + col;
      int gcol = (nn < 128) ? (h * 128 + nn) : (2048 + h * 128 + (nn - 128));
#pragma unroll
      for (int r = 0; r < 4; ++r) {
        int gm = gmb + r;
        Cpack[(size_t)(b * S_LEN + gm) * 4096 + gcol] = f2bf(acc[i][j][r]);
      }
    }
}

extern "C" void kernel_launch(void* const* d_in, const int* in_sizes, int n_in,
                              void* d_out, int out_size, void* d_ws, size_t ws_size,
                              hipStream_t stream) {
  const float* xr = (const float*)d_in[0];
  const float* xi = (const float*)d_in[1];
  const float* wq_r = (const float*)d_in[2];
  const float* wq_i = (const float*)d_in[3];
  const float* bq_r = (const float*)d_in[4];
  const float* bq_i = (const float*)d_in[5];
  const float* wk_r = (const float*)d_in[6];
  const float* wk_i = (const float*)d_in[7];
  const float* bk_r = (const float*)d_in[8];
  const float* bk_i = (const float*)d_in[9];
  const float* wv_r = (const float*)d_in[10];
  const float* wv_i = (const float*)d_in[11];
  const float* bv_r = (const float*)d_in[12];
  const float* bv_i = (const float*)d_in[13];
  const float* wo_r = (const float*)d_in[14];
  const float* wo_i = (const float*)d_in[15];
  const float* bo_r = (const float*)d_in[16];
  const float* bo_i = (const float*)d_in[17];

  float* out = (float*)d_out;
  float* outR = out;
  float* outI = out + (size_t)BATCH * S_LEN * HIDDEN;
  float* attn = outI + (size_t)BATCH * S_LEN * HIDDEN;

  char* ws = (char*)d_ws;
  size_t off = 0;
  auto alloc = [&](size_t bytes) {
    char* p = ws + off;
    off += (bytes + 255) & ~(size_t)255;
    return p;
  };
  unsigned short* Xp = (unsigned short*)alloc((size_t)4096 * 4096 * 2);
  unsigned short* Wt = (unsigned short*)alloc((size_t)10240 * 4096 * 2);
  float* QKVf = (float*)alloc((size_t)4096 * 6144 * 4);
  float* tab = (float*)alloc((size_t)S_LEN * 64 * 2 * 4);
  unsigned short* Qcat = (unsigned short*)alloc((size_t)BATCH * NHEAD * S_LEN * 256 * 2);
  unsigned short* Kcat = (unsigned short*)alloc((size_t)BATCH * NKVH * S_LEN * 256 * 2);
  unsigned short* Vt = (unsigned short*)alloc((size_t)BATCH * NKVH * 256 * S_LEN * 2);
  unsigned short* Cpack = Xp;  // reuse: Xp dead after QKV GEMM

  k_rope_table<<<512, 256, 0, stream>>>(tab);
  k_pack_x<<<16384, 256, 0, stream>>>(xr, xi, Xp);
  k_pack_w<<<dim3(128, 320), dim3(32, 8), 0, stream>>>(wq_r, wq_i, wk_r, wk_i, wv_r, wv_i,
                                                       wo_r, wo_i, Wt);
  // QKV fused GEMM: [4096,4096] @ [4096,6144]
  k_gemm<<<dim3(48, 32, 1), 256, 0, stream>>>(Xp, 4096, Wt, 4096, QKVf, 6144, 4096, 0,
                                              nullptr, nullptr, nullptr, nullptr);
  k_rope_q<<<32768, 256, 0, stream>>>(QKVf, tab, bq_r, bq_i, Qcat);
  k_rope_k<<<8192, 256, 0, stream>>>(QKVf, tab, bk_r, bk_i, Kcat);
  k_vpack<<<dim3(64, 8, 8), dim3(32, 8), 0, stream>>>(QKVf, bv_r, bv_i, Vt);
  // scores: per (b,h) [2048,256] @ [2048,256]^T, causal + scale, raw into attn
  k_gemm<<<dim3(16, 16, 32), 256, 0, stream>>>(Qcat, 256, Kcat, 256, attn, 0, 256, 2,
                                               nullptr, nullptr, nullptr, nullptr);
  k_softmax<<<dim3(2048, 32), 256, 0, stream>>>(attn);
  k_pv<<<dim3(2, 16, 32), 256, 0, stream>>>(attn, Vt, Cpack);
  // O proj: [4096,4096] @ [4096,4096], split epilogue with bias
  k_gemm<<<dim3(32, 32, 1), 256, 0, stream>>>(Cpack, 4096, Wt + (size_t)6144 * 4096, 4096,
                                              nullptr, 0, 4096, 1, outR, outI, bo_r, bo_i);
}